// Round 1
// baseline (1782.501 us; speedup 1.0000x reference)
//
#include <hip/hip_runtime.h>

#define B_ 8
#define S_ 32
#define C_ 3
#define H_ 256
#define W_ 256
#define HW_ (H_*W_)
#define CHW_ (C_*H_*W_)
#define NINROWS (B_*S_*H_)   // 65536
#define NTGROWS (B_*H_)      // 2048
#define KT 16

// -------- Phase 1: row L2 norms (one wave per 768-elem row) --------
__global__ void ct_norms(const float* __restrict__ input,
                         const float* __restrict__ target,
                         float* __restrict__ nin, float* __restrict__ ntg) {
  int gw = (int)((blockIdx.x * (size_t)blockDim.x + threadIdx.x) >> 6);
  int lane = threadIdx.x & 63;
  const float* base;
  if (gw < NINROWS) {
    int h = gw & (H_-1);
    int bs = gw >> 8;
    base = input + (size_t)bs * CHW_ + (size_t)h * W_;
  } else {
    int r = gw - NINROWS;
    int h = r & (H_-1);
    int b = r >> 8;
    base = target + (size_t)b * CHW_ + (size_t)h * W_;
  }
  float ss = 0.f;
#pragma unroll
  for (int c = 0; c < C_; ++c)
#pragma unroll
    for (int tt = 0; tt < W_/64; ++tt) {
      float v = base[c*HW_ + tt*64 + lane];
      ss = fmaf(v, v, ss);
    }
#pragma unroll
  for (int off = 32; off; off >>= 1) ss += __shfl_xor(ss, off);
  if (lane == 0) {
    float n = fmaxf(sqrtf(ss), 1e-12f);
    if (gw < NINROWS) nin[gw] = n;
    else ntg[gw - NINROWS] = n;
  }
}

// -------- Phase 2+3: per-(b,s) 256x256 GEMM (K=768) + diagonal reduce + argmax --------
// Thread tile: 16 contiguous rows x 8 strided cols (c = tc + 32*i).
// As[kk][row]  (pad 264): A-frag reads are 2-address broadcast b128.
// Bs[col][kk]  (pad 18):  B-frag reads stride 18 floats -> worst 2-way bank alias (free).
__global__ __launch_bounds__(512, 2)
void ct_corr(const float* __restrict__ input,
             const float* __restrict__ target,
             const float* __restrict__ nin,
             const float* __restrict__ ntg,
             int* __restrict__ shift_out) {
  __shared__ float As[KT][264];
  __shared__ float Bs[256][18];
  __shared__ float nin_s[256], ntg_s[256];
  __shared__ float corrS[256];
  __shared__ unsigned long long wkey[4];

  const int bs = blockIdx.x;       // b*S + s
  const int b  = bs >> 5;
  const int t  = threadIdx.x;      // 0..511
  const int tc = t & 31;
  const int tr = t >> 5;           // 0..15

  const float* Abase = input  + (size_t)bs * CHW_;
  const float* Tbase = target + (size_t)b  * CHW_;

  if (t < 256) {
    nin_s[t] = nin[bs*256 + t];
    ntg_s[t] = ntg[b*256 + t];
    corrS[t] = 0.f;
  }

  float acc[16][8];
#pragma unroll
  for (int j = 0; j < 16; ++j)
#pragma unroll
    for (int i = 0; i < 8; ++i) acc[j][i] = 0.f;

  const int j0 = t >> 2;   // row handled by this thread for staging (and j0+128)
  const int wq = t & 3;    // which float4 of the 16-float K-slice

  // register prefetch of tile 0
  float4 pa0, pa1, pb0, pb1;
  pa0 = *(const float4*)(Abase + (size_t)j0*W_ + wq*4);
  pa1 = *(const float4*)(Abase + (size_t)(j0+128)*W_ + wq*4);
  pb0 = *(const float4*)(Tbase + (size_t)j0*W_ + wq*4);
  pb1 = *(const float4*)(Tbase + (size_t)(j0+128)*W_ + wq*4);

  for (int kt = 0; kt < 48; ++kt) {
    __syncthreads();
    // stage regs -> LDS (A transposed to [kk][row]; B row-major [col][kk])
    As[wq*4+0][j0] = pa0.x; As[wq*4+1][j0] = pa0.y;
    As[wq*4+2][j0] = pa0.z; As[wq*4+3][j0] = pa0.w;
    As[wq*4+0][j0+128] = pa1.x; As[wq*4+1][j0+128] = pa1.y;
    As[wq*4+2][j0+128] = pa1.z; As[wq*4+3][j0+128] = pa1.w;
    *(float2*)&Bs[j0][wq*4]       = make_float2(pb0.x, pb0.y);
    *(float2*)&Bs[j0][wq*4+2]     = make_float2(pb0.z, pb0.w);
    *(float2*)&Bs[j0+128][wq*4]   = make_float2(pb1.x, pb1.y);
    *(float2*)&Bs[j0+128][wq*4+2] = make_float2(pb1.z, pb1.w);
    __syncthreads();
    // issue next tile's global loads (hide HBM latency under compute)
    if (kt < 47) {
      int ktn = kt + 1;
      int c  = ktn >> 4;
      int w0 = (ktn & 15) << 4;
      const float* Ab = Abase + (size_t)c*HW_ + w0;
      const float* Tb = Tbase + (size_t)c*HW_ + w0;
      pa0 = *(const float4*)(Ab + (size_t)j0*W_ + wq*4);
      pa1 = *(const float4*)(Ab + (size_t)(j0+128)*W_ + wq*4);
      pb0 = *(const float4*)(Tb + (size_t)j0*W_ + wq*4);
      pb1 = *(const float4*)(Tb + (size_t)(j0+128)*W_ + wq*4);
    }
    // compute 16 kk steps (pairs)
#pragma unroll
    for (int kk = 0; kk < KT; kk += 2) {
      float a0[16], a1[16], bb[16];
#pragma unroll
      for (int j4 = 0; j4 < 4; ++j4) {
        *(float4*)(a0 + 4*j4) = *(const float4*)&As[kk][tr*16 + 4*j4];
        *(float4*)(a1 + 4*j4) = *(const float4*)&As[kk+1][tr*16 + 4*j4];
      }
#pragma unroll
      for (int i = 0; i < 8; ++i)
        *(float2*)(bb + 2*i) = *(const float2*)&Bs[tc + 32*i][kk];
#pragma unroll
      for (int i = 0; i < 8; ++i)
#pragma unroll
        for (int j = 0; j < 16; ++j)
          acc[j][i] = fmaf(a0[j], bb[2*i], fmaf(a1[j], bb[2*i+1], acc[j][i]));
    }
  }

  // normalize + reduce upper diagonals: q = col - row >= 0
  float rn[16];
#pragma unroll
  for (int j = 0; j < 16; ++j) rn[j] = 1.0f / nin_s[tr*16 + j];
#pragma unroll
  for (int i = 0; i < 8; ++i) {
    int c = tc + 32*i;
    float rt = 1.0f / ntg_s[c];
#pragma unroll
    for (int j = 0; j < 16; ++j) {
      int q = c - (tr*16 + j);
      if (q >= 0) atomicAdd(&corrS[q], acc[j][i] * rn[j] * rt);
    }
  }
  __syncthreads();

  // argmax over p (first max wins) -> shift = q_best
  if (t < 256) {
    int q = 255 - t;                               // p = t
    float v = corrS[q] / (float)(256 - q);         // divide by overlap size p+1
    unsigned u = __float_as_uint(v);
    u = (u & 0x80000000u) ? ~u : (u | 0x80000000u);  // total order for floats
    unsigned long long key = ((unsigned long long)u << 32) | (unsigned)q; // tie -> larger q = smaller p
#pragma unroll
    for (int off = 32; off; off >>= 1) {
      unsigned long long o = __shfl_xor(key, off);
      if (o > key) key = o;
    }
    if ((t & 63) == 0) wkey[t >> 6] = key;
  }
  __syncthreads();
  if (t == 0) {
    unsigned long long k = wkey[0];
#pragma unroll
    for (int i = 1; i < 4; ++i) if (wkey[i] > k) k = wkey[i];
    shift_out[bs] = (int)(k & 0xFFFFFFFFull);
  }
}

// -------- Phase 4: shifted gather --------
__global__ void ct_gather(const float* __restrict__ input,
                          const int* __restrict__ shift,
                          float* __restrict__ out) {
  size_t idx = (size_t)blockIdx.x * blockDim.x + threadIdx.x;  // float4 units
  int w4 = (int)(idx & 63);
  int h  = (int)((idx >> 6) & 255);
  int sc = (int)(idx >> 14);        // (b*S+s)*C + c
  int bs = sc / 3;
  int hh = h + shift[bs];
  float4 v = make_float4(0.f, 0.f, 0.f, 0.f);
  if (hh < H_) v = *(const float4*)(input + ((size_t)sc << 16) + (size_t)hh * W_ + w4*4);
  *(float4*)(out + (idx << 2)) = v;
}

extern "C" void kernel_launch(void* const* d_in, const int* in_sizes, int n_in,
                              void* d_out, int out_size, void* d_ws, size_t ws_size,
                              hipStream_t stream) {
  const float* input  = (const float*)d_in[0];
  const float* target = (const float*)d_in[1];
  float* out  = (float*)d_out;
  float* nin  = (float*)d_ws;            // 65536 f
  float* ntg  = nin + NINROWS;           // 2048 f
  int*  shift = (int*)(ntg + NTGROWS);   // 256 i

  ct_norms <<<(NINROWS + NTGROWS) / 4, 256, 0, stream>>>(input, target, nin, ntg);
  ct_corr  <<<B_ * S_, 512, 0, stream>>>(input, target, nin, ntg, shift);
  ct_gather<<<(B_*S_*C_*H_*W_/4) / 256, 256, 0, stream>>>(input, shift, out);
}

// Round 2
// 190.793 us; speedup vs baseline: 9.3426x; 9.3426x over previous
//
#include <hip/hip_runtime.h>

#define B_ 8
#define S_ 32
#define C_ 3
#define H_ 256
#define W_ 256
#define HW_ (H_*W_)
#define CHW_ (C_*H_*W_)
#define NINROWS (B_*S_*H_)   // 65536
#define NTGROWS (B_*H_)      // 2048

typedef __attribute__((ext_vector_type(8))) short bf16x8;
typedef __attribute__((ext_vector_type(4))) float f32x4;

__device__ __forceinline__ ushort f2bf(float x) {
  unsigned u = __float_as_uint(x);
  return (ushort)((u + 0x7FFFu + ((u >> 16) & 1u)) >> 16);   // RNE, no NaN in data
}
__device__ __forceinline__ float bf2f(ushort h) {
  return __uint_as_float(((unsigned)h) << 16);
}

// -------- Phase 1: row L2 norms (one wave per 768-elem row) --------
__global__ void ct_norms(const float* __restrict__ input,
                         const float* __restrict__ target,
                         float* __restrict__ nin, float* __restrict__ ntg) {
  int gw = (int)((blockIdx.x * (size_t)blockDim.x + threadIdx.x) >> 6);
  int lane = threadIdx.x & 63;
  const float* base;
  if (gw < NINROWS) {
    int h = gw & (H_-1);
    int bs = gw >> 8;
    base = input + (size_t)bs * CHW_ + (size_t)h * W_;
  } else {
    int r = gw - NINROWS;
    int h = r & (H_-1);
    int b = r >> 8;
    base = target + (size_t)b * CHW_ + (size_t)h * W_;
  }
  float ss = 0.f;
#pragma unroll
  for (int c = 0; c < C_; ++c)
#pragma unroll
    for (int tt = 0; tt < W_/64; ++tt) {
      float v = base[c*HW_ + tt*64 + lane];
      ss = fmaf(v, v, ss);
    }
#pragma unroll
  for (int off = 32; off; off >>= 1) ss += __shfl_xor(ss, off);
  if (lane == 0) {
    float n = fmaxf(sqrtf(ss), 1e-12f);
    if (gw < NINROWS) nin[gw] = n;
    else ntg[gw - NINROWS] = n;
  }
}

// -------- Phase 2+3: per-(b,s) MFMA GEMM (256x256, K=768, bf16 3-term split) --------
// 8 waves, wave tile 128x64 (8x4 frags of 16x16x32). BK=32.
// LDS fragment layout [tile16][khalf(4)][idx16][8] bf16 -> frag read = ds_read_b128
// at base + lane*16 (linear, conflict-free); staging writes linear 8B/thread.
__global__ __launch_bounds__(512)
void ct_corr_mfma(const float* __restrict__ input,
                  const float* __restrict__ target,
                  const float* __restrict__ nin,
                  const float* __restrict__ ntg,
                  int* __restrict__ shift_out) {
  __shared__ ushort Ah[8192], Al[8192], Bh[8192], Bl[8192];  // 16 KB each
  __shared__ float nin_s[256], ntg_s[256], corrS[256];
  __shared__ unsigned long long wkey[4];

  const int bs = blockIdx.x;          // b*S + s
  const int b  = bs >> 5;
  const int t  = threadIdx.x;         // 0..511
  const int lane = t & 63;
  const int wid  = t >> 6;            // 0..7
  const int wm   = wid >> 2;          // 0..1 : M half (128 rows)
  const int wn   = wid & 3;           // 0..3 : N quarter (64 cols)

  const float* Abase = input  + (size_t)bs * CHW_;
  const float* Tbase = target + (size_t)b  * CHW_;

  if (t < 256) {
    nin_s[t] = nin[bs*256 + t];
    ntg_s[t] = ntg[b*256 + t];
    corrS[t] = 0.f;
  }

  f32x4 acc[8][4];
#pragma unroll
  for (int m = 0; m < 8; ++m)
#pragma unroll
    for (int n = 0; n < 4; ++n) acc[m][n] = (f32x4){0.f, 0.f, 0.f, 0.f};

  float4 pa[4], pb[4];

  // issue global loads for K-tile kt into registers
  auto issue = [&](int kt) {
    const float* Ab = Abase + (size_t)(kt >> 3) * HW_ + (kt & 7) * 32;
    const float* Tb = Tbase + (size_t)(kt >> 3) * HW_ + (kt & 7) * 32;
#pragma unroll
    for (int p = 0; p < 4; ++p) {
      int f   = p * 512 + t;
      int row = (f >> 7) * 16 + ((f >> 1) & 15);
      int kk  = ((f >> 5) & 3) * 8 + (f & 1) * 4;
      pa[p] = *(const float4*)(Ab + (size_t)row * W_ + kk);
      pb[p] = *(const float4*)(Tb + (size_t)row * W_ + kk);
    }
  };

  // convert to hi/lo bf16 and stash into LDS (linear writes)
  auto stash = [&]() {
#pragma unroll
    for (int p = 0; p < 4; ++p) {
      int f   = p * 512 + t;
      int idx = (f >> 7) * 512 + ((f >> 5) & 3) * 128 + ((f >> 1) & 15) * 8 + (f & 1) * 4;
      float4 va = pa[p], vb = pb[p];
      ushort4 hv, lv;
      hv.x = f2bf(va.x); lv.x = f2bf(va.x - bf2f(hv.x));
      hv.y = f2bf(va.y); lv.y = f2bf(va.y - bf2f(hv.y));
      hv.z = f2bf(va.z); lv.z = f2bf(va.z - bf2f(hv.z));
      hv.w = f2bf(va.w); lv.w = f2bf(va.w - bf2f(hv.w));
      *(ushort4*)&Ah[idx] = hv;
      *(ushort4*)&Al[idx] = lv;
      hv.x = f2bf(vb.x); lv.x = f2bf(vb.x - bf2f(hv.x));
      hv.y = f2bf(vb.y); lv.y = f2bf(vb.y - bf2f(hv.y));
      hv.z = f2bf(vb.z); lv.z = f2bf(vb.z - bf2f(hv.z));
      hv.w = f2bf(vb.w); lv.w = f2bf(vb.w - bf2f(hv.w));
      *(ushort4*)&Bh[idx] = hv;
      *(ushort4*)&Bl[idx] = lv;
    }
  };

  issue(0);
  for (int kt = 0; kt < 24; ++kt) {
    __syncthreads();                  // previous tile's reads complete
    stash();
    __syncthreads();
    if (kt < 23) issue(kt + 1);       // prefetch next tile under compute

    bf16x8 bh[4], bl[4];
#pragma unroll
    for (int n = 0; n < 4; ++n) {
      int ct = wn * 4 + n;
      bh[n] = *(const bf16x8*)&Bh[ct * 512 + lane * 8];
      bl[n] = *(const bf16x8*)&Bl[ct * 512 + lane * 8];
    }
#pragma unroll
    for (int m = 0; m < 8; ++m) {
      int rt = wm * 8 + m;
      bf16x8 ah = *(const bf16x8*)&Ah[rt * 512 + lane * 8];
      bf16x8 al = *(const bf16x8*)&Al[rt * 512 + lane * 8];
#pragma unroll
      for (int n = 0; n < 4; ++n) {
        acc[m][n] = __builtin_amdgcn_mfma_f32_16x16x32_bf16(ah, bh[n], acc[m][n], 0, 0, 0);
        acc[m][n] = __builtin_amdgcn_mfma_f32_16x16x32_bf16(ah, bl[n], acc[m][n], 0, 0, 0);
        acc[m][n] = __builtin_amdgcn_mfma_f32_16x16x32_bf16(al, bh[n], acc[m][n], 0, 0, 0);
      }
    }
  }

  // normalize + reduce upper diagonals (q = col - row >= 0)
#pragma unroll
  for (int n = 0; n < 4; ++n) {
    int col = wn * 64 + n * 16 + (lane & 15);
    float rc = 1.0f / ntg_s[col];
#pragma unroll
    for (int m = 0; m < 8; ++m) {
      f32x4 a = acc[m][n];
#pragma unroll
      for (int r = 0; r < 4; ++r) {
        int row = wm * 128 + m * 16 + (lane >> 4) * 4 + r;
        int q = col - row;
        if (q >= 0) atomicAdd(&corrS[q], a[r] * (1.0f / nin_s[row]) * rc);
      }
    }
  }
  __syncthreads();

  // argmax over p (first max wins) -> shift = q_best
  if (t < 256) {
    int q = 255 - t;                               // p = t
    float v = corrS[q] / (float)(256 - q);         // mean over overlap size p+1
    unsigned u = __float_as_uint(v);
    u = (u & 0x80000000u) ? ~u : (u | 0x80000000u);
    unsigned long long key = ((unsigned long long)u << 32) | (unsigned)q;
#pragma unroll
    for (int off = 32; off; off >>= 1) {
      unsigned long long o = __shfl_xor(key, off);
      if (o > key) key = o;
    }
    if ((t & 63) == 0) wkey[t >> 6] = key;
  }
  __syncthreads();
  if (t == 0) {
    unsigned long long k = wkey[0];
#pragma unroll
    for (int i = 1; i < 4; ++i) if (wkey[i] > k) k = wkey[i];
    shift_out[bs] = (int)(k & 0xFFFFFFFFull);
  }
}

// -------- Phase 4: shifted gather --------
__global__ void ct_gather(const float* __restrict__ input,
                          const int* __restrict__ shift,
                          float* __restrict__ out) {
  size_t idx = (size_t)blockIdx.x * blockDim.x + threadIdx.x;  // float4 units
  int w4 = (int)(idx & 63);
  int h  = (int)((idx >> 6) & 255);
  int sc = (int)(idx >> 14);        // (b*S+s)*C + c
  int bs = sc / 3;
  int hh = h + shift[bs];
  float4 v = make_float4(0.f, 0.f, 0.f, 0.f);
  if (hh < H_) v = *(const float4*)(input + ((size_t)sc << 16) + (size_t)hh * W_ + w4*4);
  *(float4*)(out + (idx << 2)) = v;
}

extern "C" void kernel_launch(void* const* d_in, const int* in_sizes, int n_in,
                              void* d_out, int out_size, void* d_ws, size_t ws_size,
                              hipStream_t stream) {
  const float* input  = (const float*)d_in[0];
  const float* target = (const float*)d_in[1];
  float* out  = (float*)d_out;
  float* nin  = (float*)d_ws;            // 65536 f
  float* ntg  = nin + NINROWS;           // 2048 f
  int*  shift = (int*)(ntg + NTGROWS);   // 256 i

  ct_norms     <<<(NINROWS + NTGROWS) / 4, 256, 0, stream>>>(input, target, nin, ntg);
  ct_corr_mfma <<<B_ * S_, 512, 0, stream>>>(input, target, nin, ntg, shift);
  ct_gather    <<<(B_*S_*C_*H_*W_/4) / 256, 256, 0, stream>>>(input, shift, out);
}

// Round 3
// 167.422 us; speedup vs baseline: 10.6468x; 1.1396x over previous
//
#include <hip/hip_runtime.h>

#define B_ 8
#define S_ 32
#define C_ 3
#define H_ 256
#define W_ 256
#define HW_ (H_*W_)
#define CHW_ (C_*H_*W_)

typedef __attribute__((ext_vector_type(8))) short bf16x8;
typedef __attribute__((ext_vector_type(4))) float f32x4;

// truncation-based hi/lo bf16 split of two floats, packed (x in low half, y in high)
__device__ __forceinline__ void split2(float x, float y, unsigned &hp, unsigned &lp) {
  unsigned ux = __float_as_uint(x), uy = __float_as_uint(y);
  unsigned hx = ux & 0xFFFF0000u, hy = uy & 0xFFFF0000u;
  float lx = x - __uint_as_float(hx);
  float ly = y - __uint_as_float(hy);
  hp = (ux >> 16) | hy;
  lp = (__float_as_uint(lx) >> 16) | (__float_as_uint(ly) & 0xFFFF0000u);
}

// -------- Fused: per-(b,s) MFMA GEMM (256x256, K=768, bf16 3-term split)
//          + fused row-norms + diagonal reduce + argmax --------
// 8 waves, wave tile 128x64 (8x4 frags of 16x16x32). BK=32. Double-buffered LDS,
// ONE barrier per K-tile; convert/stage of tile kt+1 and global-issue of tile kt+2
// interleave with MFMA of tile kt in a single basic block.
__global__ __launch_bounds__(512)
void ct_corr_mfma(const float* __restrict__ input,
                  const float* __restrict__ target,
                  int* __restrict__ shift_out) {
  __shared__ ushort Ah[2][8192], Al[2][8192], Bh[2][8192], Bl[2][8192];  // 128 KB
  __shared__ float ninSq[256], ntgSq[256], rnin[256], rntg[256], corrS[256];
  __shared__ unsigned long long wkey[4];

  const int bs = blockIdx.x;          // b*S + s
  const int b  = bs >> 5;
  const int t  = threadIdx.x;         // 0..511
  const int lane = t & 63;
  const int wid  = t >> 6;            // 0..7
  const int wm   = wid >> 2;          // 0..1 : M half (128 rows)
  const int wn   = wid & 3;           // 0..3 : N quarter (64 cols)

  const float* Abase = input  + (size_t)bs * CHW_;
  const float* Tbase = target + (size_t)b  * CHW_;

  if (t < 256) { ninSq[t] = 0.f; ntgSq[t] = 0.f; corrS[t] = 0.f; }

  f32x4 acc[8][4];
#pragma unroll
  for (int m = 0; m < 8; ++m)
#pragma unroll
    for (int n = 0; n < 4; ++n) acc[m][n] = (f32x4){0.f, 0.f, 0.f, 0.f};

  float4 pa[4], pb[4];
  float ssA[4] = {0.f, 0.f, 0.f, 0.f};
  float ssB[4] = {0.f, 0.f, 0.f, 0.f};

  // issue global loads for K-tile kt into registers
  auto issue = [&](int kt) {
    const float* Ab = Abase + (size_t)(kt >> 3) * HW_ + (kt & 7) * 32;
    const float* Tb = Tbase + (size_t)(kt >> 3) * HW_ + (kt & 7) * 32;
#pragma unroll
    for (int p = 0; p < 4; ++p) {
      int f   = p * 512 + t;
      int row = (f >> 7) * 16 + ((f >> 1) & 15);
      int kk  = ((f >> 5) & 3) * 8 + (f & 1) * 4;
      pa[p] = *(const float4*)(Ab + (size_t)row * W_ + kk);
      pb[p] = *(const float4*)(Tb + (size_t)row * W_ + kk);
    }
  };

  // convert to hi/lo bf16, stash into LDS buffer `sel`, accumulate norm partials
  auto stash = [&](int sel) {
    ushort* AhD = Ah[sel]; ushort* AlD = Al[sel];
    ushort* BhD = Bh[sel]; ushort* BlD = Bl[sel];
#pragma unroll
    for (int p = 0; p < 4; ++p) {
      int f   = p * 512 + t;
      int idx = (f >> 7) * 512 + ((f >> 5) & 3) * 128 + ((f >> 1) & 15) * 8 + (f & 1) * 4;
      float4 va = pa[p], vb = pb[p];
      ssA[p] = fmaf(va.x, va.x, fmaf(va.y, va.y, fmaf(va.z, va.z, fmaf(va.w, va.w, ssA[p]))));
      ssB[p] = fmaf(vb.x, vb.x, fmaf(vb.y, vb.y, fmaf(vb.z, vb.z, fmaf(vb.w, vb.w, ssB[p]))));
      unsigned h0, l0, h1, l1;
      split2(va.x, va.y, h0, l0); split2(va.z, va.w, h1, l1);
      *(uint2*)&AhD[idx] = make_uint2(h0, h1);
      *(uint2*)&AlD[idx] = make_uint2(l0, l1);
      split2(vb.x, vb.y, h0, l0); split2(vb.z, vb.w, h1, l1);
      *(uint2*)&BhD[idx] = make_uint2(h0, h1);
      *(uint2*)&BlD[idx] = make_uint2(l0, l1);
    }
  };

  issue(0);
  stash(0);
  issue(1);
  __syncthreads();

  for (int kt = 0; kt < 24; ++kt) {
    const int cur = kt & 1, nx = cur ^ 1;
    const ushort* AhC = Ah[cur]; const ushort* AlC = Al[cur];
    const ushort* BhC = Bh[cur]; const ushort* BlC = Bl[cur];

    bf16x8 bh[4], bl[4];
#pragma unroll
    for (int n = 0; n < 4; ++n) {
      int ct = wn * 4 + n;
      bh[n] = *(const bf16x8*)&BhC[ct * 512 + lane * 8];
      bl[n] = *(const bf16x8*)&BlC[ct * 512 + lane * 8];
    }
#pragma unroll
    for (int m = 0; m < 8; ++m) {
      int rt = wm * 8 + m;
      bf16x8 ah = *(const bf16x8*)&AhC[rt * 512 + lane * 8];
      bf16x8 al = *(const bf16x8*)&AlC[rt * 512 + lane * 8];
#pragma unroll
      for (int n = 0; n < 4; ++n) {
        acc[m][n] = __builtin_amdgcn_mfma_f32_16x16x32_bf16(ah, bh[n], acc[m][n], 0, 0, 0);
        acc[m][n] = __builtin_amdgcn_mfma_f32_16x16x32_bf16(ah, bl[n], acc[m][n], 0, 0, 0);
        acc[m][n] = __builtin_amdgcn_mfma_f32_16x16x32_bf16(al, bh[n], acc[m][n], 0, 0, 0);
      }
    }
    // overlap with MFMA above (same basic block): stage tile kt+1, issue tile kt+2
    if (kt < 23) stash(nx);
    if (kt < 22) issue(kt + 2);
    __syncthreads();
  }

  // fused norms: each thread staged 4 fixed A-rows and 4 fixed B-rows across all K
#pragma unroll
  for (int p = 0; p < 4; ++p) {
    int row = (p * 4 + (t >> 7)) * 16 + ((t >> 1) & 15);
    atomicAdd(&ninSq[row], ssA[p]);
    atomicAdd(&ntgSq[row], ssB[p]);
  }
  __syncthreads();
  if (t < 256) {
    rnin[t] = 1.0f / fmaxf(sqrtf(ninSq[t]), 1e-12f);
    rntg[t] = 1.0f / fmaxf(sqrtf(ntgSq[t]), 1e-12f);
  }
  __syncthreads();

  // normalize + reduce upper diagonals (q = col - row >= 0)
#pragma unroll
  for (int n = 0; n < 4; ++n) {
    int col = wn * 64 + n * 16 + (lane & 15);
    float rc = rntg[col];
#pragma unroll
    for (int m = 0; m < 8; ++m) {
      f32x4 a = acc[m][n];
#pragma unroll
      for (int r = 0; r < 4; ++r) {
        int row = wm * 128 + m * 16 + (lane >> 4) * 4 + r;
        int q = col - row;
        if (q >= 0) atomicAdd(&corrS[q], a[r] * rnin[row] * rc);
      }
    }
  }
  __syncthreads();

  // argmax over p (first max wins) -> shift = q_best
  if (t < 256) {
    int q = 255 - t;                               // p = t
    float v = corrS[q] / (float)(256 - q);         // mean over overlap size p+1
    unsigned u = __float_as_uint(v);
    u = (u & 0x80000000u) ? ~u : (u | 0x80000000u);
    unsigned long long key = ((unsigned long long)u << 32) | (unsigned)q;
#pragma unroll
    for (int off = 32; off; off >>= 1) {
      unsigned long long o = __shfl_xor(key, off);
      if (o > key) key = o;
    }
    if ((t & 63) == 0) wkey[t >> 6] = key;
  }
  __syncthreads();
  if (t == 0) {
    unsigned long long k = wkey[0];
#pragma unroll
    for (int i = 1; i < 4; ++i) if (wkey[i] > k) k = wkey[i];
    shift_out[bs] = (int)(k & 0xFFFFFFFFull);
  }
}

// -------- shifted gather --------
__global__ void ct_gather(const float* __restrict__ input,
                          const int* __restrict__ shift,
                          float* __restrict__ out) {
  size_t idx = (size_t)blockIdx.x * blockDim.x + threadIdx.x;  // float4 units
  int w4 = (int)(idx & 63);
  int h  = (int)((idx >> 6) & 255);
  int sc = (int)(idx >> 14);        // (b*S+s)*C + c
  int bs = sc / 3;
  int hh = h + shift[bs];
  float4 v = make_float4(0.f, 0.f, 0.f, 0.f);
  if (hh < H_) v = *(const float4*)(input + ((size_t)sc << 16) + (size_t)hh * W_ + w4*4);
  *(float4*)(out + (idx << 2)) = v;
}

extern "C" void kernel_launch(void* const* d_in, const int* in_sizes, int n_in,
                              void* d_out, int out_size, void* d_ws, size_t ws_size,
                              hipStream_t stream) {
  const float* input  = (const float*)d_in[0];
  const float* target = (const float*)d_in[1];
  float* out  = (float*)d_out;
  int*  shift = (int*)d_ws;

  ct_corr_mfma <<<B_ * S_, 512, 0, stream>>>(input, target, shift);
  ct_gather    <<<(B_*S_*C_*H_*W_/4) / 256, 256, 0, stream>>>(input, shift, out);
}